// Round 1
// baseline (925.330 us; speedup 1.0000x reference)
//
#include <hip/hip_runtime.h>
#include <hip/hip_bf16.h>

#define N_ROWS 100000
#define F_VS 28
#define HIDN 64
#define OUT_F 768
#define NCLS 4
#define VMAXC 64

typedef __attribute__((ext_vector_type(8))) short short8;
typedef __attribute__((ext_vector_type(4))) float floatx4;

// ---- workspace layout (bytes) ----
// [0,       28672)  counts  int[256*28]
// [28672,   28688)  class_size int[4]
// [28928,  127232)  wfc bf16 [768*64]
// [131072, ...)     h bf16 [N*64]  (12.8 MB)

__device__ __forceinline__ float frcp(float x) { return __builtin_amdgcn_rcpf(x); }
__device__ __forceinline__ float sigm(float x) { return frcp(1.f + __expf(-x)); }
__device__ __forceinline__ float tanh_f(float x) { return 1.f - 2.f * frcp(__expf(2.f * x) + 1.f); }

// Kernel 1: joint (class,value)-per-column histogram + class sizes + W_fc -> bf16
__global__ __launch_bounds__(256) void k_hist(const float* __restrict__ VS,
                                              const int* __restrict__ Level,
                                              const float* __restrict__ Wfc,
                                              int* __restrict__ counts,
                                              int* __restrict__ cls,
                                              __hip_bfloat16* __restrict__ wfc16) {
    __shared__ int lc[NCLS * VMAXC * F_VS];   // 7168 ints = 28 KB
    __shared__ int lcls[NCLS];
    int tid = threadIdx.x;
    for (int i = tid; i < NCLS * VMAXC * F_VS; i += 256) lc[i] = 0;
    if (tid < NCLS) lcls[tid] = 0;

    int gtid = blockIdx.x * 256 + tid;
    int gsz = gridDim.x * 256;
    // W_fc fp32 -> bf16 (independent work, amortized here)
    for (int i = gtid; i < OUT_F * HIDN; i += gsz)
        wfc16[i] = __float2bfloat16(Wfc[i]);
    __syncthreads();

    for (int i = gtid; i < N_ROWS; i += gsz) {
        int lab = Level[i];
        atomicAdd(&lcls[lab], 1);
        const float4* row = (const float4*)(VS + (size_t)i * F_VS);  // 112B rows, 16B aligned
#pragma unroll
        for (int q = 0; q < 7; q++) {
            float4 v4 = row[q];
            int c = q * 4;
            atomicAdd(&lc[((lab << 6) + (int)v4.x) * F_VS + c + 0], 1);
            atomicAdd(&lc[((lab << 6) + (int)v4.y) * F_VS + c + 1], 1);
            atomicAdd(&lc[((lab << 6) + (int)v4.z) * F_VS + c + 2], 1);
            atomicAdd(&lc[((lab << 6) + (int)v4.w) * F_VS + c + 3], 1);
        }
    }
    __syncthreads();
    for (int i = tid; i < NCLS * VMAXC * F_VS; i += 256) {
        int v = lc[i];
        if (v) atomicAdd(&counts[i], v);
    }
    if (tid < NCLS) {
        int v = lcls[tid];
        if (v) atomicAdd(&cls[tid], v);
    }
}

// Kernel 2: casual-weight + LSTM cell (len-1 seq, c0=h0=0 => f-gate dead) -> h bf16
// One wave per row; gate weights for this lane's 3 live gates live in VGPRs.
__global__ __launch_bounds__(256) void k_lstm(const float* __restrict__ VS,
                                              const int* __restrict__ Level,
                                              const int* __restrict__ Depart,
                                              const float* __restrict__ Wih,
                                              const float* __restrict__ bih,
                                              const float* __restrict__ bhh,
                                              const int* __restrict__ counts,
                                              const int* __restrict__ cls,
                                              __hip_bfloat16* __restrict__ h16,
                                              float* __restrict__ outL,
                                              float* __restrict__ outD) {
    int tid = threadIdx.x;
    int gtid = blockIdx.x * 256 + tid;

    // Level / Depart passthrough (exact as float)
    if (gtid < N_ROWS) {
        outL[gtid] = (float)Level[gtid];
        outD[gtid] = (float)Depart[gtid];
    }

    int lane = tid & 63;
    int wib = tid >> 6;                    // wave index in block
    int w = gtid >> 6;                     // global wave id
    int nw = (gridDim.x * 256) >> 6;

    // torch gate order i,f,g,o -> rows {lane, 128+lane, 192+lane} of W_ih (f unused)
    float w0[F_VS], w2[F_VS], w3[F_VS];
#pragma unroll
    for (int j = 0; j < F_VS; j++) {
        w0[j] = Wih[(0 * HIDN + lane) * F_VS + j];
        w2[j] = Wih[(2 * HIDN + lane) * F_VS + j];
        w3[j] = Wih[(3 * HIDN + lane) * F_VS + j];
    }
    float b0 = bih[0 * HIDN + lane] + bhh[0 * HIDN + lane];
    float b2 = bih[2 * HIDN + lane] + bhh[2 * HIDN + lane];
    float b3 = bih[3 * HIDN + lane] + bhh[3 * HIDN + lane];

    __shared__ float xsh[4][64];           // one row per wave; b128 broadcast reads

    for (int r = w; r < N_ROWS; r += nw) {
        int lab = Level[r];
        float inv = frcp((float)cls[lab]);
        float xv = 0.f;
        if (lane < F_VS) {
            float v = VS[(size_t)r * F_VS + lane];
            int vi = (int)v;
            int cnt = counts[(((lab << 6) | vi)) * F_VS + lane];
            xv = v * ((float)cnt * inv);
        }
        xsh[wib][lane] = xv;               // all 64 lanes write (28..63 write 0)
        __asm__ volatile("" ::: "memory"); // keep ds_write before ds_reads (in-order LDS pipe)

        float a0 = b0, a2 = b2, a3 = b3;
#pragma unroll
        for (int q = 0; q < 7; q++) {
            floatx4 xq = *(const floatx4*)(&xsh[wib][q * 4]);
            a0 = fmaf(xq[0], w0[4 * q + 0], a0);
            a0 = fmaf(xq[1], w0[4 * q + 1], a0);
            a0 = fmaf(xq[2], w0[4 * q + 2], a0);
            a0 = fmaf(xq[3], w0[4 * q + 3], a0);
            a2 = fmaf(xq[0], w2[4 * q + 0], a2);
            a2 = fmaf(xq[1], w2[4 * q + 1], a2);
            a2 = fmaf(xq[2], w2[4 * q + 2], a2);
            a2 = fmaf(xq[3], w2[4 * q + 3], a2);
            a3 = fmaf(xq[0], w3[4 * q + 0], a3);
            a3 = fmaf(xq[1], w3[4 * q + 1], a3);
            a3 = fmaf(xq[2], w3[4 * q + 2], a3);
            a3 = fmaf(xq[3], w3[4 * q + 3], a3);
        }
        __asm__ volatile("" ::: "memory"); // don't sink next row's ds_write above these reads

        float c = sigm(a0) * tanh_f(a2);
        float h = sigm(a3) * tanh_f(c);
        h16[(size_t)r * HIDN + lane] = __float2bfloat16(h);
    }
}

// Kernel 3: vs_feat = h[N,64] @ W_fc^T[64,768] + b_fc via mfma_f32_16x16x32_bf16
// One wave per 16-row tile, loops all 48 column tiles (A frags loaded once).
__global__ __launch_bounds__(256) void k_gemm(const __hip_bfloat16* __restrict__ h16,
                                              const __hip_bfloat16* __restrict__ wfc16,
                                              const float* __restrict__ bfc,
                                              float* __restrict__ outV) {
    int tid = threadIdx.x;
    int lane = tid & 63;
    int w = (blockIdx.x * 256 + tid) >> 6;
    int nw = (gridDim.x * 256) >> 6;
    int quad = lane >> 4;    // 0..3
    int l16 = lane & 15;
    const int nm = N_ROWS / 16;  // 6250 exact

    for (int mt = w; mt < nm; mt += nw) {
        int row0 = mt * 16;
        // A[m=l16][k=quad*8+j] ; two K-blocks of 32
        const short* hA = (const short*)(h16 + (size_t)(row0 + l16) * HIDN + quad * 8);
        short8 a0 = *(const short8*)(hA);
        short8 a1 = *(const short8*)(hA + 32);
        for (int nt = 0; nt < OUT_F / 16; nt++) {
            // B[k=quad*8+j][n=l16] = W_fc[n][k] -> contiguous in k
            const short* pB = (const short*)(wfc16 + (size_t)(nt * 16 + l16) * HIDN + quad * 8);
            short8 bf0 = *(const short8*)(pB);
            short8 bf1 = *(const short8*)(pB + 32);
            floatx4 acc = {0.f, 0.f, 0.f, 0.f};
            acc = __builtin_amdgcn_mfma_f32_16x16x32_bf16(a0, bf0, acc, 0, 0, 0);
            acc = __builtin_amdgcn_mfma_f32_16x16x32_bf16(a1, bf1, acc, 0, 0, 0);
            float bias = bfc[nt * 16 + l16];
            // C: col = lane&15, row = quad*4 + reg
#pragma unroll
            for (int rr = 0; rr < 4; rr++) {
                outV[(size_t)(row0 + quad * 4 + rr) * OUT_F + nt * 16 + l16] = acc[rr] + bias;
            }
        }
    }
}

// Kernel 4: cc_feat = squeeze(CC) -> straight float4 copy
__global__ __launch_bounds__(256) void k_copy(const float4* __restrict__ src,
                                              float4* __restrict__ dst, int n4) {
    int i = blockIdx.x * blockDim.x + threadIdx.x;
    int s = gridDim.x * blockDim.x;
    for (; i < n4; i += s) dst[i] = src[i];
}

extern "C" void kernel_launch(void* const* d_in, const int* in_sizes, int n_in,
                              void* d_out, int out_size, void* d_ws, size_t ws_size,
                              hipStream_t stream) {
    const float* VS = (const float*)d_in[0];
    const float* CC = (const float*)d_in[1];
    const int* Level = (const int*)d_in[2];
    const int* Depart = (const int*)d_in[3];
    const float* Wih = (const float*)d_in[4];
    // d_in[5] = W_hh unused (h0 = 0)
    const float* bih = (const float*)d_in[6];
    const float* bhh = (const float*)d_in[7];
    const float* Wfc = (const float*)d_in[8];
    const float* bfc = (const float*)d_in[9];

    float* out = (float*)d_out;
    char* ws = (char*)d_ws;
    int* counts = (int*)ws;
    int* cls = (int*)(ws + 28672);
    __hip_bfloat16* wfc16 = (__hip_bfloat16*)(ws + 28928);
    __hip_bfloat16* h16 = (__hip_bfloat16*)(ws + 131072);

    float* outCC = out;
    float* outV = out + (size_t)N_ROWS * OUT_F;
    float* outL = out + (size_t)2 * N_ROWS * OUT_F;
    float* outD = outL + N_ROWS;

    hipMemsetAsync(d_ws, 0, 28688, stream);  // zero counts + class_size
    k_hist<<<64, 256, 0, stream>>>(VS, Level, Wfc, counts, cls, wfc16);
    k_lstm<<<800, 256, 0, stream>>>(VS, Level, Depart, Wih, bih, bhh, counts, cls, h16, outL, outD);
    k_gemm<<<512, 256, 0, stream>>>(h16, wfc16, bfc, outV);
    k_copy<<<2048, 256, 0, stream>>>((const float4*)CC, (float4*)outCC,
                                     (N_ROWS * OUT_F) / 4);
}

// Round 2
// 890.885 us; speedup vs baseline: 1.0387x; 1.0387x over previous
//
#include <hip/hip_runtime.h>
#include <hip/hip_bf16.h>

#define N_ROWS 100000
#define F_VS 28
#define HIDN 64
#define OUT_F 768
#define NCLS 4
#define VMAXC 64

// fused-kernel grid split: tile blocks do lstm+gemm, copy blocks stream CC
#define TILE_BLOCKS 1563            // 1563 * 4 waves = 6252 >= 6250 row-tiles
#define COPY_BLOCKS 485
#define GRID_FUSED (TILE_BLOCKS + COPY_BLOCKS)

typedef __attribute__((ext_vector_type(8))) short short8;
typedef __attribute__((ext_vector_type(4))) float floatx4;

// ---- workspace layout (bytes) ----
// [0,       28672)  counts  int[256*28]
// [28672,   28688)  class_size int[4]
// [28928,  127232)  wfc bf16 [768*64]

__device__ __forceinline__ float frcp(float x) { return __builtin_amdgcn_rcpf(x); }
__device__ __forceinline__ float sigm(float x) { return frcp(1.f + __expf(-x)); }
__device__ __forceinline__ float tanh_f(float x) { return 1.f - 2.f * frcp(__expf(2.f * x) + 1.f); }

// Kernel 1: joint (class,value)-per-column histogram + class sizes + W_fc -> bf16
__global__ __launch_bounds__(256) void k_hist(const float* __restrict__ VS,
                                              const int* __restrict__ Level,
                                              const float* __restrict__ Wfc,
                                              int* __restrict__ counts,
                                              int* __restrict__ cls,
                                              __hip_bfloat16* __restrict__ wfc16) {
    __shared__ int lc[NCLS * VMAXC * F_VS];   // 7168 ints = 28 KB
    __shared__ int lcls[NCLS];
    int tid = threadIdx.x;
    for (int i = tid; i < NCLS * VMAXC * F_VS; i += 256) lc[i] = 0;
    if (tid < NCLS) lcls[tid] = 0;

    int gtid = blockIdx.x * 256 + tid;
    int gsz = gridDim.x * 256;
    // W_fc fp32 -> bf16 (independent work, amortized here)
    for (int i = gtid; i < OUT_F * HIDN; i += gsz)
        wfc16[i] = __float2bfloat16(Wfc[i]);
    __syncthreads();

    for (int i = gtid; i < N_ROWS; i += gsz) {
        int lab = Level[i];
        atomicAdd(&lcls[lab], 1);
        const float4* row = (const float4*)(VS + (size_t)i * F_VS);  // 112B rows, 16B aligned
#pragma unroll
        for (int q = 0; q < 7; q++) {
            float4 v4 = row[q];
            int c = q * 4;
            atomicAdd(&lc[((lab << 6) + (int)v4.x) * F_VS + c + 0], 1);
            atomicAdd(&lc[((lab << 6) + (int)v4.y) * F_VS + c + 1], 1);
            atomicAdd(&lc[((lab << 6) + (int)v4.z) * F_VS + c + 2], 1);
            atomicAdd(&lc[((lab << 6) + (int)v4.w) * F_VS + c + 3], 1);
        }
    }
    __syncthreads();
    for (int i = tid; i < NCLS * VMAXC * F_VS; i += 256) {
        int v = lc[i];
        if (v) atomicAdd(&counts[i], v);
    }
    if (tid < NCLS) {
        int v = lcls[tid];
        if (v) atomicAdd(&cls[tid], v);
    }
}

// Kernel 2 (fused): casual-weight + LSTM -> h in LDS -> MFMA gemm -> vs_feat,
// concurrently other blocks stream cc_feat copy + Level/Depart passthrough.
__global__ __launch_bounds__(256) void k_fused(const float* __restrict__ VS,
                                               const int* __restrict__ Level,
                                               const int* __restrict__ Depart,
                                               const float* __restrict__ Wih,
                                               const float* __restrict__ bih,
                                               const float* __restrict__ bhh,
                                               const int* __restrict__ counts,
                                               const int* __restrict__ cls,
                                               const __hip_bfloat16* __restrict__ wfc16,
                                               const float* __restrict__ bfc,
                                               const float4* __restrict__ CC,
                                               float4* __restrict__ outCC,
                                               float* __restrict__ outV,
                                               float* __restrict__ outL,
                                               float* __restrict__ outD) {
    int tid = threadIdx.x;

    if (blockIdx.x >= TILE_BLOCKS) {
        // ---- copy role: cc_feat = squeeze(CC), plus Level/Depart passthrough ----
        int cb = blockIdx.x - TILE_BLOCKS;
        int ctid = cb * 256 + tid;
        int csz = COPY_BLOCKS * 256;
        for (int i = ctid; i < N_ROWS; i += csz) {
            outL[i] = (float)Level[i];
            outD[i] = (float)Depart[i];
        }
        const int n4 = (N_ROWS * OUT_F) / 4;   // 19.2M float4
        for (int i = ctid; i < n4; i += csz) outCC[i] = CC[i];
        return;
    }

    // ---- tile role: one wave owns one 16-row tile ----
    int lane = tid & 63;
    int wib = tid >> 6;
    int wave = blockIdx.x * 4 + wib;
    const int nm = N_ROWS / 16;  // 6250 exact
    if (wave >= nm) return;

    // torch gate order i,f,g,o -> rows {lane, 128+lane, 192+lane} of W_ih (f dead: c0=0)
    float w0[F_VS], w2[F_VS], w3[F_VS];
#pragma unroll
    for (int j = 0; j < F_VS; j++) {
        w0[j] = Wih[(0 * HIDN + lane) * F_VS + j];
        w2[j] = Wih[(2 * HIDN + lane) * F_VS + j];
        w3[j] = Wih[(3 * HIDN + lane) * F_VS + j];
    }
    float b0 = bih[0 * HIDN + lane] + bhh[0 * HIDN + lane];
    float b2 = bih[2 * HIDN + lane] + bhh[2 * HIDN + lane];
    float b3 = bih[3 * HIDN + lane] + bhh[3 * HIDN + lane];

    __shared__ float xsh[4][64];       // one row per wave; broadcast reads
    __shared__ short hsh[4][16][72];   // h tile, bf16 bits; stride 72 -> 2-way bank alias only

    int row0 = wave * 16;
#pragma unroll 1
    for (int i = 0; i < 16; i++) {
        int r = row0 + i;
        int lab = Level[r];
        float inv = frcp((float)cls[lab]);
        float xv = 0.f;
        if (lane < F_VS) {
            float v = VS[(size_t)r * F_VS + lane];
            int vi = (int)v;
            int cnt = counts[(((lab << 6) | vi)) * F_VS + lane];
            xv = v * ((float)cnt * inv);
        }
        xsh[wib][lane] = xv;               // all 64 lanes write (28..63 write 0)
        __asm__ volatile("" ::: "memory"); // keep ds_write before ds_reads

        float a0 = b0, a2 = b2, a3 = b3;
#pragma unroll
        for (int q = 0; q < 7; q++) {
            floatx4 xq = *(const floatx4*)(&xsh[wib][q * 4]);
            a0 = fmaf(xq[0], w0[4 * q + 0], a0);
            a0 = fmaf(xq[1], w0[4 * q + 1], a0);
            a0 = fmaf(xq[2], w0[4 * q + 2], a0);
            a0 = fmaf(xq[3], w0[4 * q + 3], a0);
            a2 = fmaf(xq[0], w2[4 * q + 0], a2);
            a2 = fmaf(xq[1], w2[4 * q + 1], a2);
            a2 = fmaf(xq[2], w2[4 * q + 2], a2);
            a2 = fmaf(xq[3], w2[4 * q + 3], a2);
            a3 = fmaf(xq[0], w3[4 * q + 0], a3);
            a3 = fmaf(xq[1], w3[4 * q + 1], a3);
            a3 = fmaf(xq[2], w3[4 * q + 2], a3);
            a3 = fmaf(xq[3], w3[4 * q + 3], a3);
        }
        __asm__ volatile("" ::: "memory"); // don't sink next row's ds_write above reads

        float c = sigm(a0) * tanh_f(a2);
        float h = sigm(a3) * tanh_f(c);
        __hip_bfloat16 hb = __float2bfloat16(h);
        hsh[wib][i][lane] = *(short*)&hb;
    }
    __asm__ volatile("" ::: "memory");     // h tile writes before A-frag reads

    // ---- gemm: A = h tile (LDS), B = W_fc^T (L1-resident 96KB), 16x16x32 mfma ----
    int quad = lane >> 4;    // 0..3
    int l16 = lane & 15;
    // A[m=l16][k=quad*8+j], two K-halves
    const short* hA = &hsh[wib][l16][quad * 8];
    short8 a0v = *(const short8*)(hA);
    short8 a1v = *(const short8*)(hA + 32);

    for (int nt = 0; nt < OUT_F / 16; nt++) {
        // B[k=quad*8+j][n=l16] = W_fc[n][k] -> contiguous in k
        const short* pB = (const short*)(wfc16 + (size_t)(nt * 16 + l16) * HIDN + quad * 8);
        short8 bf0 = *(const short8*)(pB);
        short8 bf1 = *(const short8*)(pB + 32);
        floatx4 acc = {0.f, 0.f, 0.f, 0.f};
        acc = __builtin_amdgcn_mfma_f32_16x16x32_bf16(a0v, bf0, acc, 0, 0, 0);
        acc = __builtin_amdgcn_mfma_f32_16x16x32_bf16(a1v, bf1, acc, 0, 0, 0);
        float bias = bfc[nt * 16 + l16];
        // C: col = lane&15, row = quad*4 + reg
#pragma unroll
        for (int rr = 0; rr < 4; rr++) {
            outV[(size_t)(row0 + quad * 4 + rr) * OUT_F + nt * 16 + l16] = acc[rr] + bias;
        }
    }
}

extern "C" void kernel_launch(void* const* d_in, const int* in_sizes, int n_in,
                              void* d_out, int out_size, void* d_ws, size_t ws_size,
                              hipStream_t stream) {
    const float* VS = (const float*)d_in[0];
    const float* CC = (const float*)d_in[1];
    const int* Level = (const int*)d_in[2];
    const int* Depart = (const int*)d_in[3];
    const float* Wih = (const float*)d_in[4];
    // d_in[5] = W_hh unused (h0 = 0)
    const float* bih = (const float*)d_in[6];
    const float* bhh = (const float*)d_in[7];
    const float* Wfc = (const float*)d_in[8];
    const float* bfc = (const float*)d_in[9];

    float* out = (float*)d_out;
    char* ws = (char*)d_ws;
    int* counts = (int*)ws;
    int* cls = (int*)(ws + 28672);
    __hip_bfloat16* wfc16 = (__hip_bfloat16*)(ws + 28928);

    float* outCC = out;
    float* outV = out + (size_t)N_ROWS * OUT_F;
    float* outL = out + (size_t)2 * N_ROWS * OUT_F;
    float* outD = outL + N_ROWS;

    hipMemsetAsync(d_ws, 0, 28688, stream);  // zero counts + class_size
    k_hist<<<64, 256, 0, stream>>>(VS, Level, Wfc, counts, cls, wfc16);
    k_fused<<<GRID_FUSED, 256, 0, stream>>>(VS, Level, Depart, Wih, bih, bhh,
                                            counts, cls, wfc16, bfc,
                                            (const float4*)CC, (float4*)outCC,
                                            outV, outL, outD);
}